// Round 10
// baseline (289.552 us; speedup 1.0000x reference)
//
#include <hip/hip_runtime.h>
#include <math.h>

// Chained bilinear lookup: out = bilinear(grid0, bilinear(grid1, x)),
// sigmoid per corner sample (both stages).
//
// Shapes: x (N,2) f32; grid1 (U1,U1,2) f32, U1=2080; grid0 (U0,U0,3) f32,
// U0=520; out (N,3) f32.
//
// PRECISION CONTRACT (rounds 0-5, PASSING at absmax 3.9e-3 / thr 1.96e-2):
//  - Ref is a faithful per-op float32 numpy pipeline; stage-1 output is
//    multiplied by 520 in stage 2 (errors amplified ~520x).
//  - su = x*U must be a SINGLE f32 rounded mul (inline-asm v_mul_f32 —
//    fast-math otherwise contracts su-floor into fma => 0.04 absmax).
//  - Table sigmoids via f64 exp + f64 divide, rounded once to f32.
//  - f32 blends as written (R5/R8-validated).
//
// PERF HISTORY:
//  R5: 2 lines/pt stage-1, FETCH 600MB, query 179us (3.4 TB/s line rate).
//  R7: padded grid0 (4.3MB) overflowed 4MB/XCD L2 -> FETCH 752MB, 222us.
//  R8: corner-packed stage-1 (32B cell, 1 line/pt): FETCH 312MB, query
//      123us; pack 137us (exp-bound: 34.6M f64 sigmoids).
//  R9: 2pt/thread query REGRESSED (VGPR=20 -> compiler serialized the two
//      gather chains, no MLP); LDS-tiled pack stayed 134us because
//      NONTEMPORAL 16B-strided stores bypassed L2 write-combining (~4x
//      HBM write amplification).
//  R10 (this): pack = LDS-tiled + PLAIN stores (L2 combines). Query =
//      1pt/thread + SoA stage-2 planes (dwordx2 per row-pair): random
//      vmem requests 14 -> 8 per point (request-rate bound: R8 ran at
//      ~1.3 cyc/request vs 1/cyc TCP ceiling).

typedef float f32x2 __attribute__((ext_vector_type(2)));
typedef float f32x4 __attribute__((ext_vector_type(4)));

__device__ __forceinline__ float mul_rn_nocontract(float a, float b) {
    float r;
    asm("v_mul_f32 %0, %1, %2" : "=v"(r) : "v"(a), "v"(b));
    return r;
}

__device__ __forceinline__ float sigmoid_f64(float t) {
    double e = exp(-(double)t);          // f64 exp: no fast-math shortcut
    return (float)(1.0 / (1.0 + e));     // f64 divide, round once to f32
}

__device__ __forceinline__ float sigmoid_fast(float t) {
    return 1.0f / (1.0f + __expf(-t));   // non-amplified use only
}

// 8B load at 4B alignment (emits global_load_dwordx2; HW tolerates
// dword alignment — R7 validated 8B-aligned dwordx4 on this chip)
__device__ __forceinline__ f32x2 load2(const float* p) {
    f32x2 v;
    __builtin_memcpy(&v, p, 8);
    return v;
}

// ---- Phase A1: LDS-tiled corner-pack of grid1 ----
// 16x16 cells per workgroup; 17x17 corner points sigmoided once into LDS,
// then each thread assembles its cell's 8 packed floats:
//   cell (u,v) -> [s(t00).xy s(t01).xy | s(t10).xy s(t11).xy]
// PLAIN stores (32B contiguous per thread, 512B per 16 lanes): L2 combines.
__global__ void __launch_bounds__(256) pack_tiled_kernel(
    const float* __restrict__ g1, float* __restrict__ pk,
    int U1, int tiles_per_row)
{
    __shared__ float sx[17][17];
    __shared__ float sy[17][17];

    int tile = blockIdx.x;
    int tu = tile / tiles_per_row;
    int tv = tile - tu * tiles_per_row;
    int ubase = tu * 16, vbase = tv * 16;

    const float2* g = reinterpret_cast<const float2*>(g1);
    for (int idx = threadIdx.x; idx < 17 * 17; idx += 256) {
        int du = idx / 17, dv = idx - du * 17;
        int u = ubase + du; if (u >= U1) u -= U1;   // wrap (ubase < U1)
        int v = vbase + dv; if (v >= U1) v -= U1;
        float2 t = g[(size_t)u * U1 + v];
        sx[du][dv] = sigmoid_f64(t.x);
        sy[du][dv] = sigmoid_f64(t.y);
    }
    __syncthreads();

    int lu = threadIdx.x >> 4, lv = threadIdx.x & 15;
    int u = ubase + lu, v = vbase + lv;
    if (u >= U1 || v >= U1) return;                 // ragged edge guard
    float4 lo = make_float4(sx[lu][lv],     sy[lu][lv],
                            sx[lu][lv + 1], sy[lu][lv + 1]);
    float4 hi = make_float4(sx[lu + 1][lv],     sy[lu + 1][lv],
                            sx[lu + 1][lv + 1], sy[lu + 1][lv + 1]);
    float4* o = reinterpret_cast<float4*>(pk + ((size_t)u * U1 + v) * 8);
    o[0] = lo;
    o[1] = hi;
}

// ---- Phase A2: sigmoid grid0 into 3 SoA planes ----
__global__ void __launch_bounds__(256) sigmoid_soa_kernel(
    const float* __restrict__ g0,
    float* __restrict__ pr, float* __restrict__ pg, float* __restrict__ pb,
    int ncells)
{
    int j = blockIdx.x * blockDim.x + threadIdx.x;
    if (j >= ncells) return;
    pr[j] = sigmoid_f64(g0[3 * j + 0]);
    pg[j] = sigmoid_f64(g0[3 * j + 1]);
    pb[j] = sigmoid_f64(g0[3 * j + 2]);
}

// ---- Phase B: query, 1 pt/thread, packed stage-1, SoA stage-2 ----
__global__ void __launch_bounds__(256) query_soa_kernel(
    const float* __restrict__ x,
    const float* __restrict__ pk,   // packed corners, U1*U1*8 floats
    const float* __restrict__ pr,   // sigmoid(grid0) channel planes
    const float* __restrict__ pg,
    const float* __restrict__ pb,
    float* __restrict__ out,        // (N,3)
    int N, int U1, int U0)
{
    int i = blockIdx.x * blockDim.x + threadIdx.x;
    if (i >= N) return;

    f32x2 uv = __builtin_nontemporal_load(
        reinterpret_cast<const f32x2*>(x) + i);

    // stage-1 coords: single rounded f32 mul (contract-proof)
    float fU1 = (float)U1;
    float su = mul_rn_nocontract(uv.x, fU1);
    float sv = mul_rn_nocontract(uv.y, fU1);
    float u0f = floorf(su), v0f = floorf(sv);
    float fu = su - u0f;              // exact
    float fv = sv - v0f;
    int u0 = (int)u0f % U1; if (u0 < 0) u0 += U1;
    int v0 = (int)v0f % U1; if (v0 < 0) v0 += U1;

    // ONE 64B line: 32B-aligned packed cell (2 dwordx4, same line)
    const float4* cell = reinterpret_cast<const float4*>(pk)
                       + (size_t)(u0 * U1 + v0) * 2;
    float4 lo = cell[0];   // t00.xy t01.xy
    float4 hi = cell[1];   // t10.xy t11.xy

    float omfu = 1.0f - fu, omfv = 1.0f - fv;
    float kx = (lo.x * omfu + hi.x * fu) * omfv
             + (lo.z * omfu + hi.z * fu) * fv;
    float ky = (lo.y * omfu + hi.y * fu) * omfv
             + (lo.w * omfu + hi.w * fu) * fv;

    // stage 2: SoA planes, one dwordx2 per (row, channel)
    float fU0 = (float)U0;
    float su2 = mul_rn_nocontract(kx, fU0);
    float sv2 = mul_rn_nocontract(ky, fU0);
    float u0f2 = floorf(su2), v0f2 = floorf(sv2);
    float fu2 = su2 - u0f2, fv2 = sv2 - v0f2;
    int p0 = (int)u0f2 % U0; if (p0 < 0) p0 += U0;
    int q0 = (int)v0f2 % U0; if (q0 < 0) q0 += U0;
    int p1 = p0 + 1; if (p1 >= U0) p1 = 0;
    bool qwrap = (q0 == U0 - 1);

    int rowA = p0 * U0 + q0;
    int rowB = p1 * U0 + q0;
    // planes padded so the 8B read at the last element stays in-bounds
    f32x2 ra = load2(pr + rowA), rb = load2(pr + rowB);
    f32x2 ga = load2(pg + rowA), gb = load2(pg + rowB);
    f32x2 ba = load2(pb + rowA), bb = load2(pb + rowB);
    if (qwrap) {                      // rare: col q1 wraps to 0
        int wA = p0 * U0, wB = p1 * U0;
        ra.y = pr[wA]; rb.y = pr[wB];
        ga.y = pg[wA]; gb.y = pg[wB];
        ba.y = pb[wA]; bb.y = pb[wB];
    }

    float omfu2 = 1.0f - fu2, omfv2 = 1.0f - fv2;
    // .x = (p,q0) corner, .y = (p,q1) corner; a = row p0, b = row p1
    float r0 = (ra.x * omfu2 + rb.x * fu2) * omfv2
             + (ra.y * omfu2 + rb.y * fu2) * fv2;
    float r1 = (ga.x * omfu2 + gb.x * fu2) * omfv2
             + (ga.y * omfu2 + gb.y * fu2) * fv2;
    float r2 = (ba.x * omfu2 + bb.x * fu2) * omfv2
             + (ba.y * omfu2 + bb.y * fu2) * fv2;

    out[3 * i + 0] = r0;
    out[3 * i + 1] = r1;
    out[3 * i + 2] = r2;
}

// ---- Middle variant: R5's known-good unpadded query kernel ----
__global__ void __launch_bounds__(256) query_kernel_unpadded(
    const float* __restrict__ x,
    const float* __restrict__ s1,
    const float* __restrict__ s0,
    float* __restrict__ out,
    int N, int U1, int U0)
{
    int i = blockIdx.x * blockDim.x + threadIdx.x;
    if (i >= N) return;
    float2 uv = reinterpret_cast<const float2*>(x)[i];
    float fU1 = (float)U1;
    float su = mul_rn_nocontract(uv.x, fU1);
    float sv = mul_rn_nocontract(uv.y, fU1);
    float u0f = floorf(su), v0f = floorf(sv);
    float fu = su - u0f, fv = sv - v0f;
    int u0 = (int)u0f % U1; if (u0 < 0) u0 += U1;
    int v0 = (int)v0f % U1; if (v0 < 0) v0 += U1;
    int u1 = u0 + 1; if (u1 >= U1) u1 = 0;
    int v1 = v0 + 1; if (v1 >= U1) v1 = 0;
    const float2* s1v = reinterpret_cast<const float2*>(s1);
    float2 t00 = s1v[u0 * U1 + v0];
    float2 t10 = s1v[u1 * U1 + v0];
    float2 t01 = s1v[u0 * U1 + v1];
    float2 t11 = s1v[u1 * U1 + v1];
    float omfu = 1.0f - fu, omfv = 1.0f - fv;
    float kx = (t00.x * omfu + t10.x * fu) * omfv + (t01.x * omfu + t11.x * fu) * fv;
    float ky = (t00.y * omfu + t10.y * fu) * omfv + (t01.y * omfu + t11.y * fu) * fv;
    float fU0 = (float)U0;
    float su2 = mul_rn_nocontract(kx, fU0);
    float sv2 = mul_rn_nocontract(ky, fU0);
    float u0f2 = floorf(su2), v0f2 = floorf(sv2);
    float fu2 = su2 - u0f2, fv2 = sv2 - v0f2;
    int p0 = (int)u0f2 % U0; if (p0 < 0) p0 += U0;
    int q0 = (int)v0f2 % U0; if (q0 < 0) q0 += U0;
    int p1 = p0 + 1; if (p1 >= U0) p1 = 0;
    int q1 = q0 + 1; if (q1 >= U0) q1 = 0;
    int b00 = (p0 * U0 + q0) * 3, b10 = (p1 * U0 + q0) * 3;
    int b01 = (p0 * U0 + q1) * 3, b11 = (p1 * U0 + q1) * 3;
    float omfu2 = 1.0f - fu2, omfv2 = 1.0f - fv2;
    float r0 = (s0[b00+0] * omfu2 + s0[b10+0] * fu2) * omfv2
             + (s0[b01+0] * omfu2 + s0[b11+0] * fu2) * fv2;
    float r1 = (s0[b00+1] * omfu2 + s0[b10+1] * fu2) * omfv2
             + (s0[b01+1] * omfu2 + s0[b11+1] * fu2) * fv2;
    float r2 = (s0[b00+2] * omfu2 + s0[b10+2] * fu2) * omfv2
             + (s0[b01+2] * omfu2 + s0[b11+2] * fu2) * fv2;
    out[3*i+0] = r0; out[3*i+1] = r1; out[3*i+2] = r2;
}

__global__ void __launch_bounds__(256) sigmoid_table_kernel(
    const float4* __restrict__ in, float4* __restrict__ out, int n4)
{
    int i = blockIdx.x * blockDim.x + threadIdx.x;
    if (i >= n4) return;
    float4 v = in[i];
    float4 r;
    r.x = sigmoid_f64(v.x);
    r.y = sigmoid_f64(v.y);
    r.z = sigmoid_f64(v.z);
    r.w = sigmoid_f64(v.w);
    out[i] = r;
}

// ---- Full fallback: all sigmoids in-kernel (ws too small) ----
__global__ void __launch_bounds__(256) query_kernel_fallback(
    const float* __restrict__ x,
    const float* __restrict__ g1,
    const float* __restrict__ g0,
    float* __restrict__ out,
    int N, int U1, int U0)
{
    int i = blockIdx.x * blockDim.x + threadIdx.x;
    if (i >= N) return;
    float2 uv = reinterpret_cast<const float2*>(x)[i];
    float fU1 = (float)U1;
    float su = mul_rn_nocontract(uv.x, fU1);
    float sv = mul_rn_nocontract(uv.y, fU1);
    float u0f = floorf(su), v0f = floorf(sv);
    float fu = su - u0f, fv = sv - v0f;
    int u0 = (int)u0f % U1; if (u0 < 0) u0 += U1;
    int v0 = (int)v0f % U1; if (v0 < 0) v0 += U1;
    int u1 = u0 + 1; if (u1 >= U1) u1 = 0;
    int v1 = v0 + 1; if (v1 >= U1) v1 = 0;
    const float2* g1v = reinterpret_cast<const float2*>(g1);
    float2 t00 = g1v[u0 * U1 + v0];
    float2 t10 = g1v[u1 * U1 + v0];
    float2 t01 = g1v[u0 * U1 + v1];
    float2 t11 = g1v[u1 * U1 + v1];
    float a00x = sigmoid_f64(t00.x), a00y = sigmoid_f64(t00.y);
    float a10x = sigmoid_f64(t10.x), a10y = sigmoid_f64(t10.y);
    float a01x = sigmoid_f64(t01.x), a01y = sigmoid_f64(t01.y);
    float a11x = sigmoid_f64(t11.x), a11y = sigmoid_f64(t11.y);
    float omfu = 1.0f - fu, omfv = 1.0f - fv;
    float kx = (a00x * omfu + a10x * fu) * omfv + (a01x * omfu + a11x * fu) * fv;
    float ky = (a00y * omfu + a10y * fu) * omfv + (a01y * omfu + a11y * fu) * fv;
    float fU0 = (float)U0;
    float su2 = mul_rn_nocontract(kx, fU0);
    float sv2 = mul_rn_nocontract(ky, fU0);
    float u0f2 = floorf(su2), v0f2 = floorf(sv2);
    float fu2 = su2 - u0f2, fv2 = sv2 - v0f2;
    int p0 = (int)u0f2 % U0; if (p0 < 0) p0 += U0;
    int q0 = (int)v0f2 % U0; if (q0 < 0) q0 += U0;
    int p1 = p0 + 1; if (p1 >= U0) p1 = 0;
    int q1 = q0 + 1; if (q1 >= U0) q1 = 0;
    int b00 = (p0 * U0 + q0) * 3, b10 = (p1 * U0 + q0) * 3;
    int b01 = (p0 * U0 + q1) * 3, b11 = (p1 * U0 + q1) * 3;
    float omfu2 = 1.0f - fu2, omfv2 = 1.0f - fv2;
    float r0 = (sigmoid_fast(g0[b00+0]) * omfu2 + sigmoid_fast(g0[b10+0]) * fu2) * omfv2
             + (sigmoid_fast(g0[b01+0]) * omfu2 + sigmoid_fast(g0[b11+0]) * fu2) * fv2;
    float r1 = (sigmoid_fast(g0[b00+1]) * omfu2 + sigmoid_fast(g0[b10+1]) * fu2) * omfv2
             + (sigmoid_fast(g0[b01+1]) * omfu2 + sigmoid_fast(g0[b11+1]) * fu2) * fv2;
    float r2 = (sigmoid_fast(g0[b00+2]) * omfu2 + sigmoid_fast(g0[b10+2]) * fu2) * omfv2
             + (sigmoid_fast(g0[b01+2]) * omfu2 + sigmoid_fast(g0[b11+2]) * fu2) * fv2;
    out[3*i+0] = r0; out[3*i+1] = r1; out[3*i+2] = r2;
}

extern "C" void kernel_launch(void* const* d_in, const int* in_sizes, int n_in,
                              void* d_out, int out_size, void* d_ws, size_t ws_size,
                              hipStream_t stream) {
    const float* x  = (const float*)d_in[0];
    const float* g1 = (const float*)d_in[1];
    const float* g0 = (const float*)d_in[2];
    float* out = (float*)d_out;

    int N = in_sizes[0] / 2;
    long long n1 = in_sizes[1];          // U1*U1*2
    long long n0 = in_sizes[2];          // U0*U0*3
    int U1 = (int)(sqrt((double)(n1 / 2)) + 0.5);
    int U0 = (int)(sqrt((double)(n0 / 3)) + 0.5);
    long long ncells1 = (long long)U1 * U1;
    long long ncells0 = (long long)U0 * U0;
    long long pstride = ncells0 + 16;    // +pad: 8B tail read stays in-bounds

    int block = 256;
    size_t need_soa   = ((size_t)ncells1 * 8 + 3 * (size_t)pstride) * sizeof(float);
    size_t need_plain = ((size_t)n1 + (size_t)n0) * sizeof(float);

    if (ws_size >= need_soa) {
        float* pk = (float*)d_ws;                     // 138.4 MB packed
        float* pr = pk + ncells1 * 8;                 // 3 x 1.08 MB planes
        float* pg = pr + pstride;
        float* pb = pg + pstride;
        int tiles_per_row = (U1 + 15) / 16;
        int ntiles = tiles_per_row * tiles_per_row;
        pack_tiled_kernel<<<ntiles, block, 0, stream>>>(g1, pk, U1, tiles_per_row);
        sigmoid_soa_kernel<<<(int)((ncells0 + block - 1) / block), block, 0, stream>>>(
            g0, pr, pg, pb, (int)ncells0);
        query_soa_kernel<<<(N + block - 1) / block, block, 0, stream>>>(
            x, pk, pr, pg, pb, out, N, U1, U0);
    } else if (ws_size >= need_plain && (n1 % 4) == 0 && (n0 % 4) == 0) {
        float* s1 = (float*)d_ws;
        float* s0 = s1 + n1;
        int n1_4 = (int)(n1 / 4), n0_4 = (int)(n0 / 4);
        sigmoid_table_kernel<<<(n1_4 + block - 1) / block, block, 0, stream>>>(
            (const float4*)g1, (float4*)s1, n1_4);
        sigmoid_table_kernel<<<(n0_4 + block - 1) / block, block, 0, stream>>>(
            (const float4*)g0, (float4*)s0, n0_4);
        query_kernel_unpadded<<<(N + block - 1) / block, block, 0, stream>>>(
            x, s1, s0, out, N, U1, U0);
    } else {
        query_kernel_fallback<<<(N + block - 1) / block, block, 0, stream>>>(
            x, g1, g0, out, N, U1, U0);
    }
}

// Round 11
// 256.066 us; speedup vs baseline: 1.1308x; 1.1308x over previous
//
#include <hip/hip_runtime.h>
#include <math.h>

// Chained bilinear lookup: out = bilinear(grid0, bilinear(grid1, x)),
// sigmoid per corner sample (both stages).
//
// Shapes: x (N,2) f32; grid1 (U1,U1,2) f32, U1=2080; grid0 (U0,U0,3) f32,
// U0=520; out (N,3) f32.
//
// PRECISION CONTRACT (R0-R10, passing at absmax 3.9e-3 / thr 1.96e-2):
//  - Ref is a faithful per-op float32 numpy pipeline; stage-1 output is
//    multiplied by 520 in stage 2 (errors amplified ~520x).
//  - su = x*U must be a SINGLE f32 rounded mul (inline-asm v_mul_f32 —
//    default ffp-contract otherwise fuses su-floor into fma => 0.04).
//  - Sigmoid: e = expf(-t) in f32 (1 ulp, matches np.exp-f32), then
//    1/(1+e) in f64 rounded once to f32. (R1/R2's 0.031 failure was the
//    COORD contraction, not exp — budget: 520 * 1ulp(sigmoid) ~ 5e-5.)
//  - f32 blends as written (R5/R8-validated).
//
// PERF HISTORY:
//  R5: 2 lines/pt stage-1, FETCH 600MB, query 179us.
//  R7: padded grid0 (4.3MB) overflowed 4MB/XCD L2 -> 752MB, 222us.
//  R8: corner-packed stage-1 (32B cell, 1 line/pt): FETCH 312MB, query
//      123us (BEST query shape); pack 137us.
//  R9: 2pt/thread -> compiler serialized chains (VGPR 20), 150us. FAIL.
//  R10: SoA stage-2 -> 6 lines vs AoS ~2 lines, 157us. FAIL. Pack still
//      ~130us with plain stores -> f64 exp() is the pack bottleneck.
//  R11 (this): query = R8 exact; all table sigmoids switch f64-exp ->
//      f32-expf + f64 divide (~10x cheaper, still ~1ulp).

typedef float f32x2 __attribute__((ext_vector_type(2)));
typedef float f32x4 __attribute__((ext_vector_type(4)));

__device__ __forceinline__ float mul_rn_nocontract(float a, float b) {
    float r;
    asm("v_mul_f32 %0, %1, %2" : "=v"(r) : "v"(a), "v"(b));
    return r;
}

// ~1-ulp sigmoid matching numpy's f32 chain: e rounded to f32 (like
// np.exp on float32), then a single correctly-rounded divide (f64 math
// is immune to any rcp/fast lowering of f32 division).
__device__ __forceinline__ float sigmoid_ref(float t) {
    float e = expf(-t);                      // ocml expf, ~1 ulp f32
    return (float)(1.0 / (1.0 + (double)e)); // exact add+div, one rounding
}

// ---- Phase A1: LDS-tiled corner-pack of grid1 ----
// 16x16 cells per workgroup; 17x17 corner points sigmoided once into LDS,
// then each thread assembles its cell's 8 packed floats:
//   cell (u,v) -> [s(t00).xy s(t01).xy | s(t10).xy s(t11).xy]
__global__ void __launch_bounds__(256) pack_tiled_kernel(
    const float* __restrict__ g1, float* __restrict__ pk,
    int U1, int tiles_per_row)
{
    __shared__ float sx[17][17];
    __shared__ float sy[17][17];

    int tile = blockIdx.x;
    int tu = tile / tiles_per_row;
    int tv = tile - tu * tiles_per_row;
    int ubase = tu * 16, vbase = tv * 16;

    const float2* g = reinterpret_cast<const float2*>(g1);
    for (int idx = threadIdx.x; idx < 17 * 17; idx += 256) {
        int du = idx / 17, dv = idx - du * 17;
        int u = ubase + du; if (u >= U1) u -= U1;   // wrap (ubase < U1)
        int v = vbase + dv; if (v >= U1) v -= U1;
        float2 t = g[(size_t)u * U1 + v];
        sx[du][dv] = sigmoid_ref(t.x);
        sy[du][dv] = sigmoid_ref(t.y);
    }
    __syncthreads();

    int lu = threadIdx.x >> 4, lv = threadIdx.x & 15;
    int u = ubase + lu, v = vbase + lv;
    if (u >= U1 || v >= U1) return;                 // ragged edge guard
    float4 lo = make_float4(sx[lu][lv],     sy[lu][lv],
                            sx[lu][lv + 1], sy[lu][lv + 1]);
    float4 hi = make_float4(sx[lu + 1][lv],     sy[lu + 1][lv],
                            sx[lu + 1][lv + 1], sy[lu + 1][lv + 1]);
    float4* o = reinterpret_cast<float4*>(pk + ((size_t)u * U1 + v) * 8);
    o[0] = lo;
    o[1] = hi;
}

// ---- Phase A2: elementwise sigmoid of a table (float4-vectorized) ----
__global__ void __launch_bounds__(256) sigmoid_table_kernel(
    const float4* __restrict__ in, float4* __restrict__ out, int n4)
{
    int i = blockIdx.x * blockDim.x + threadIdx.x;
    if (i >= n4) return;
    float4 v = in[i];
    float4 r;
    r.x = sigmoid_ref(v.x);
    r.y = sigmoid_ref(v.y);
    r.z = sigmoid_ref(v.z);
    r.w = sigmoid_ref(v.w);
    out[i] = r;
}

// ---- Phase B: R8's query (1 pt/thread, packed stage-1, AoS stage-2) ----
__global__ void __launch_bounds__(256) query_packed_kernel(
    const float* __restrict__ x,
    const float* __restrict__ pk,   // packed corners, U1*U1*8 floats
    const float* __restrict__ s0,   // sigmoid(grid0), (U0,U0,3), L2-resident
    float* __restrict__ out,        // (N,3)
    int N, int U1, int U0)
{
    int i = blockIdx.x * blockDim.x + threadIdx.x;
    if (i >= N) return;

    f32x2 uv = __builtin_nontemporal_load(
        reinterpret_cast<const f32x2*>(x) + i);

    // stage-1 coords: single rounded f32 mul (contract-proof)
    float fU1 = (float)U1;
    float su = mul_rn_nocontract(uv.x, fU1);
    float sv = mul_rn_nocontract(uv.y, fU1);
    float u0f = floorf(su), v0f = floorf(sv);
    float fu = su - u0f;              // exact
    float fv = sv - v0f;
    int u0 = (int)u0f % U1; if (u0 < 0) u0 += U1;
    int v0 = (int)v0f % U1; if (v0 < 0) v0 += U1;

    // ONE 64B line: 32B-aligned packed cell
    const float4* cell = reinterpret_cast<const float4*>(pk)
                       + (size_t)(u0 * U1 + v0) * 2;
    float4 lo = cell[0];   // t00.xy t01.xy
    float4 hi = cell[1];   // t10.xy t11.xy

    float omfu = 1.0f - fu, omfv = 1.0f - fv;
    float kx = (lo.x * omfu + hi.x * fu) * omfv
             + (lo.z * omfu + hi.z * fu) * fv;
    float ky = (lo.y * omfu + hi.y * fu) * omfv
             + (lo.w * omfu + hi.w * fu) * fv;

    // stage 2 (R5/R8-validated form, L2-resident 3.2MB AoS table)
    float fU0 = (float)U0;
    float su2 = mul_rn_nocontract(kx, fU0);
    float sv2 = mul_rn_nocontract(ky, fU0);
    float u0f2 = floorf(su2), v0f2 = floorf(sv2);
    float fu2 = su2 - u0f2, fv2 = sv2 - v0f2;
    int p0 = (int)u0f2 % U0; if (p0 < 0) p0 += U0;
    int q0 = (int)v0f2 % U0; if (q0 < 0) q0 += U0;
    int p1 = p0 + 1; if (p1 >= U0) p1 = 0;
    int q1 = q0 + 1; if (q1 >= U0) q1 = 0;
    int b00 = (p0 * U0 + q0) * 3, b10 = (p1 * U0 + q0) * 3;
    int b01 = (p0 * U0 + q1) * 3, b11 = (p1 * U0 + q1) * 3;
    float omfu2 = 1.0f - fu2, omfv2 = 1.0f - fv2;
    float r0 = (s0[b00+0] * omfu2 + s0[b10+0] * fu2) * omfv2
             + (s0[b01+0] * omfu2 + s0[b11+0] * fu2) * fv2;
    float r1 = (s0[b00+1] * omfu2 + s0[b10+1] * fu2) * omfv2
             + (s0[b01+1] * omfu2 + s0[b11+1] * fu2) * fv2;
    float r2 = (s0[b00+2] * omfu2 + s0[b10+2] * fu2) * omfv2
             + (s0[b01+2] * omfu2 + s0[b11+2] * fu2) * fv2;
    out[3*i+0] = r0; out[3*i+1] = r1; out[3*i+2] = r2;
}

// ---- Middle variant: R5's known-good unpadded query kernel ----
__global__ void __launch_bounds__(256) query_kernel_unpadded(
    const float* __restrict__ x,
    const float* __restrict__ s1,
    const float* __restrict__ s0,
    float* __restrict__ out,
    int N, int U1, int U0)
{
    int i = blockIdx.x * blockDim.x + threadIdx.x;
    if (i >= N) return;
    float2 uv = reinterpret_cast<const float2*>(x)[i];
    float fU1 = (float)U1;
    float su = mul_rn_nocontract(uv.x, fU1);
    float sv = mul_rn_nocontract(uv.y, fU1);
    float u0f = floorf(su), v0f = floorf(sv);
    float fu = su - u0f, fv = sv - v0f;
    int u0 = (int)u0f % U1; if (u0 < 0) u0 += U1;
    int v0 = (int)v0f % U1; if (v0 < 0) v0 += U1;
    int u1 = u0 + 1; if (u1 >= U1) u1 = 0;
    int v1 = v0 + 1; if (v1 >= U1) v1 = 0;
    const float2* s1v = reinterpret_cast<const float2*>(s1);
    float2 t00 = s1v[u0 * U1 + v0];
    float2 t10 = s1v[u1 * U1 + v0];
    float2 t01 = s1v[u0 * U1 + v1];
    float2 t11 = s1v[u1 * U1 + v1];
    float omfu = 1.0f - fu, omfv = 1.0f - fv;
    float kx = (t00.x * omfu + t10.x * fu) * omfv + (t01.x * omfu + t11.x * fu) * fv;
    float ky = (t00.y * omfu + t10.y * fu) * omfv + (t01.y * omfu + t11.y * fu) * fv;
    float fU0 = (float)U0;
    float su2 = mul_rn_nocontract(kx, fU0);
    float sv2 = mul_rn_nocontract(ky, fU0);
    float u0f2 = floorf(su2), v0f2 = floorf(sv2);
    float fu2 = su2 - u0f2, fv2 = sv2 - v0f2;
    int p0 = (int)u0f2 % U0; if (p0 < 0) p0 += U0;
    int q0 = (int)v0f2 % U0; if (q0 < 0) q0 += U0;
    int p1 = p0 + 1; if (p1 >= U0) p1 = 0;
    int q1 = q0 + 1; if (q1 >= U0) q1 = 0;
    int b00 = (p0 * U0 + q0) * 3, b10 = (p1 * U0 + q0) * 3;
    int b01 = (p0 * U0 + q1) * 3, b11 = (p1 * U0 + q1) * 3;
    float omfu2 = 1.0f - fu2, omfv2 = 1.0f - fv2;
    float r0 = (s0[b00+0] * omfu2 + s0[b10+0] * fu2) * omfv2
             + (s0[b01+0] * omfu2 + s0[b11+0] * fu2) * fv2;
    float r1 = (s0[b00+1] * omfu2 + s0[b10+1] * fu2) * omfv2
             + (s0[b01+1] * omfu2 + s0[b11+1] * fu2) * fv2;
    float r2 = (s0[b00+2] * omfu2 + s0[b10+2] * fu2) * omfv2
             + (s0[b01+2] * omfu2 + s0[b11+2] * fu2) * fv2;
    out[3*i+0] = r0; out[3*i+1] = r1; out[3*i+2] = r2;
}

// ---- Full fallback: all sigmoids in-kernel (ws too small) ----
__global__ void __launch_bounds__(256) query_kernel_fallback(
    const float* __restrict__ x,
    const float* __restrict__ g1,
    const float* __restrict__ g0,
    float* __restrict__ out,
    int N, int U1, int U0)
{
    int i = blockIdx.x * blockDim.x + threadIdx.x;
    if (i >= N) return;
    float2 uv = reinterpret_cast<const float2*>(x)[i];
    float fU1 = (float)U1;
    float su = mul_rn_nocontract(uv.x, fU1);
    float sv = mul_rn_nocontract(uv.y, fU1);
    float u0f = floorf(su), v0f = floorf(sv);
    float fu = su - u0f, fv = sv - v0f;
    int u0 = (int)u0f % U1; if (u0 < 0) u0 += U1;
    int v0 = (int)v0f % U1; if (v0 < 0) v0 += U1;
    int u1 = u0 + 1; if (u1 >= U1) u1 = 0;
    int v1 = v0 + 1; if (v1 >= U1) v1 = 0;
    const float2* g1v = reinterpret_cast<const float2*>(g1);
    float2 t00 = g1v[u0 * U1 + v0];
    float2 t10 = g1v[u1 * U1 + v0];
    float2 t01 = g1v[u0 * U1 + v1];
    float2 t11 = g1v[u1 * U1 + v1];
    float a00x = sigmoid_ref(t00.x), a00y = sigmoid_ref(t00.y);
    float a10x = sigmoid_ref(t10.x), a10y = sigmoid_ref(t10.y);
    float a01x = sigmoid_ref(t01.x), a01y = sigmoid_ref(t01.y);
    float a11x = sigmoid_ref(t11.x), a11y = sigmoid_ref(t11.y);
    float omfu = 1.0f - fu, omfv = 1.0f - fv;
    float kx = (a00x * omfu + a10x * fu) * omfv + (a01x * omfu + a11x * fu) * fv;
    float ky = (a00y * omfu + a10y * fu) * omfv + (a01y * omfu + a11y * fu) * fv;
    float fU0 = (float)U0;
    float su2 = mul_rn_nocontract(kx, fU0);
    float sv2 = mul_rn_nocontract(ky, fU0);
    float u0f2 = floorf(su2), v0f2 = floorf(sv2);
    float fu2 = su2 - u0f2, fv2 = sv2 - v0f2;
    int p0 = (int)u0f2 % U0; if (p0 < 0) p0 += U0;
    int q0 = (int)v0f2 % U0; if (q0 < 0) q0 += U0;
    int p1 = p0 + 1; if (p1 >= U0) p1 = 0;
    int q1 = q0 + 1; if (q1 >= U0) q1 = 0;
    int b00 = (p0 * U0 + q0) * 3, b10 = (p1 * U0 + q0) * 3;
    int b01 = (p0 * U0 + q1) * 3, b11 = (p1 * U0 + q1) * 3;
    float omfu2 = 1.0f - fu2, omfv2 = 1.0f - fv2;
    float r0 = (sigmoid_ref(g0[b00+0]) * omfu2 + sigmoid_ref(g0[b10+0]) * fu2) * omfv2
             + (sigmoid_ref(g0[b01+0]) * omfu2 + sigmoid_ref(g0[b11+0]) * fu2) * fv2;
    float r1 = (sigmoid_ref(g0[b00+1]) * omfu2 + sigmoid_ref(g0[b10+1]) * fu2) * omfv2
             + (sigmoid_ref(g0[b01+1]) * omfu2 + sigmoid_ref(g0[b11+1]) * fu2) * fv2;
    float r2 = (sigmoid_ref(g0[b00+2]) * omfu2 + sigmoid_ref(g0[b10+2]) * fu2) * omfv2
             + (sigmoid_ref(g0[b01+2]) * omfu2 + sigmoid_ref(g0[b11+2]) * fu2) * fv2;
    out[3*i+0] = r0; out[3*i+1] = r1; out[3*i+2] = r2;
}

extern "C" void kernel_launch(void* const* d_in, const int* in_sizes, int n_in,
                              void* d_out, int out_size, void* d_ws, size_t ws_size,
                              hipStream_t stream) {
    const float* x  = (const float*)d_in[0];
    const float* g1 = (const float*)d_in[1];
    const float* g0 = (const float*)d_in[2];
    float* out = (float*)d_out;

    int N = in_sizes[0] / 2;
    long long n1 = in_sizes[1];          // U1*U1*2
    long long n0 = in_sizes[2];          // U0*U0*3
    int U1 = (int)(sqrt((double)(n1 / 2)) + 0.5);
    int U0 = (int)(sqrt((double)(n0 / 3)) + 0.5);
    long long ncells1 = (long long)U1 * U1;

    int block = 256;
    size_t need_packed = ((size_t)ncells1 * 8 + (size_t)n0) * sizeof(float);
    size_t need_plain  = ((size_t)n1 + (size_t)n0) * sizeof(float);

    if (ws_size >= need_packed && (n0 % 4) == 0) {
        float* pk = (float*)d_ws;                     // 138.4 MB packed
        float* s0 = pk + ncells1 * 8;                 // 3.2 MB sigmoided g0
        int n0_4 = (int)(n0 / 4);
        int tiles_per_row = (U1 + 15) / 16;
        int ntiles = tiles_per_row * tiles_per_row;
        pack_tiled_kernel<<<ntiles, block, 0, stream>>>(g1, pk, U1, tiles_per_row);
        sigmoid_table_kernel<<<(n0_4 + block - 1) / block, block, 0, stream>>>(
            (const float4*)g0, (float4*)s0, n0_4);
        query_packed_kernel<<<(N + block - 1) / block, block, 0, stream>>>(
            x, pk, s0, out, N, U1, U0);
    } else if (ws_size >= need_plain && (n1 % 4) == 0 && (n0 % 4) == 0) {
        float* s1 = (float*)d_ws;
        float* s0 = s1 + n1;
        int n1_4 = (int)(n1 / 4), n0_4 = (int)(n0 / 4);
        sigmoid_table_kernel<<<(n1_4 + block - 1) / block, block, 0, stream>>>(
            (const float4*)g1, (float4*)s1, n1_4);
        sigmoid_table_kernel<<<(n0_4 + block - 1) / block, block, 0, stream>>>(
            (const float4*)g0, (float4*)s0, n0_4);
        query_kernel_unpadded<<<(N + block - 1) / block, block, 0, stream>>>(
            x, s1, s0, out, N, U1, U0);
    } else {
        query_kernel_fallback<<<(N + block - 1) / block, block, 0, stream>>>(
            x, g1, g0, out, N, U1, U0);
    }
}